// Round 3
// baseline (170.373 us; speedup 1.0000x reference)
//
#include <hip/hip_runtime.h>
#include <math.h>

namespace {

constexpr int kB    = 16384;
constexpr int kS0   = 7;
constexpr int kS1   = 7;
constexpr int kD    = 30;
constexpr int kCells = kB * kS0 * kS1;   // 802816
constexpr int TPB   = 256;
constexpr int CPB   = 256;               // cells per block (1 cell / thread)
constexpr int NBLK  = kCells / CPB;      // 3136 (exact)
constexpr int TILE_F  = CPB * kD;        // 7680 floats staged per block
constexpr int TILE_V4 = TILE_F / 4;      // 1920 float4 per block (7.5 * 256)
constexpr float kInv7 = 1.0f / 7.0f;
constexpr float kWC = 5.0f;
constexpr float kWN = 0.5f;

__device__ __forceinline__ float frcp(float x) {
    return __builtin_amdgcn_rcpf(x);     // v_rcp_f32, ~1e-7 rel err (2% tol)
}

__device__ __forceinline__ float sigm(float x) {
    return frcp(1.0f + __expf(-x));
}

// global -> LDS direct (dwordx4): no VGPR round-trip, no address VALU.
// LDS dest is wave-uniform base + lane*16 (HW semantics), so the tile is
// staged LINEAR (stride 30 floats/cell). Stride-30 reads are a 4-way bank
// conflict (~1.58x on the ds ops) -- accepted, it overlaps the HBM stream.
__device__ __forceinline__ void load_lds16(const float4* g, float* lds) {
    __builtin_amdgcn_global_load_lds(
        (const __attribute__((address_space(1))) void*)g,
        (__attribute__((address_space(3))) void*)lds,
        16, 0, 0);
}

// r13 == r12 with the hipMemsetAsync (suspected graph-capture tripwire in
// the failed r12 run) replaced by a 1-block zeroing kernel.
//  - staging: 7.5 dwordx4-batches/thread straight to linear LDS (zero VALU,
//    zero VGPR traffic); tail batch is wave-uniform predicated (waves 0,1).
//  - finish_kernel dropped: per-block atomicAdd into out[0]; 3136
//    same-address atomics arrive spread over the kernel lifetime (no tail
//    dispatch waiting on full-grid drain).
//  - LDS 30720B -> 5 blocks/CU; launch_bounds(256,5) caps VGPR, compute
//    phase streams from LDS so pressure is low.
__global__ void zero_kernel(float* __restrict__ out) {
    if (threadIdx.x == 0) out[0] = 0.0f;
}

__global__ void __launch_bounds__(TPB, 5) yolo_loss_kernel(
    const float* __restrict__ pred,
    const int*   __restrict__ grid,
    const float* __restrict__ tbox,
    const int*   __restrict__ tcls,
    float* __restrict__ out)
{
    __shared__ float sp[TILE_F];          // 30,720 B linear tile
    __shared__ float wsum[TPB / 64];

    const int tid  = threadIdx.x;
    const int cell = blockIdx.x * CPB + tid;
    const int wave = tid >> 6;
    const int lane = tid & 63;

    // per-cell side loads: stride == width -> fully coalesced; issued first
    // so they resolve under the staging phase.
    const float4 tb4 = reinterpret_cast<const float4*>(tbox)[cell];
    const int g  = grid[cell];
    const int tc = tcls[cell];

    // ---- staging: 1920 contiguous float4 -> linear LDS, direct ----
    const float4* __restrict__ gp4 =
        reinterpret_cast<const float4*>(pred + (size_t)blockIdx.x * TILE_F);
    #pragma unroll
    for (int b = 0; b < 8; ++b) {
        if (b < 7 || wave < 2) {          // tail: waves 0,1 (wave-uniform)
            load_lds16(gp4 + b * 256 + tid, &sp[b * 1024 + wave * 256]);
        }
    }
    __syncthreads();                      // compiler emits vmcnt(0) drain

    // ---- per-cell compute, streaming from LDS (stride 30) ----
    const float* __restrict__ fb = &sp[tid * kD];

    const int cj = cell % kS1;            // column -> xg
    const int ci = (cell / kS1) % kS0;    // row    -> yg
    const float tox = tb4.x, toy = tb4.y, tw = tb4.z, th = tb4.w;

    const float conf0 = sigm(fb[0]);
    const float conf1 = sigm(fb[1]);
    float pbx[2], pby[2], pbw[2], pbh[2];
    #pragma unroll
    for (int k = 0; k < 2; ++k) {
        pbx[k] = sigm(fb[2 + 4 * k + 0]);
        pby[k] = sigm(fb[2 + 4 * k + 1]);
        pbw[k] = sigm(fb[2 + 4 * k + 2]);
        pbh[k] = sigm(fb[2 + 4 * k + 3]);
    }

    // softmax over 20 classes, no max-subtraction (inputs ~N(0,1):
    // exp <= ~e^6, 20-term fp32 sum nowhere near overflow)
    float csum = 0.0f, et = 0.0f;
    #pragma unroll
    for (int q = 0; q < 20; ++q) {
        const float e = __expf(fb[10 + q]);
        csum += e;
        et = (q == tc) ? e : et;          // constant q -> cndmask
    }
    const float cls_t = et * frcp(csum);

    // IOU of both predicted boxes vs target box
    const float x = (float)cj, y = (float)ci;
    const float tcx = (x + tox) * kInv7;
    const float tcy = (y + toy) * kInv7;
    const float thw = tw * 0.5f, thh = th * 0.5f;
    const float tarea = tw * th;

    float iou[2];
    #pragma unroll
    for (int k = 0; k < 2; ++k) {
        const float pcx = (x + pbx[k]) * kInv7;
        const float pcy = (y + pby[k]) * kInv7;
        const float pw = pbw[k], ph = pbh[k];
        const float tb_ = fminf(tcx + thw, pcx + pw * 0.5f) - fmaxf(tcx - thw, pcx - pw * 0.5f);
        const float lr_ = fminf(tcy + thh, pcy + ph * 0.5f) - fmaxf(tcy - thh, pcy - ph * 0.5f);
        float inter = tb_ * lr_;
        inter = (tb_ < 0.0f || lr_ < 0.0f) ? 0.0f : inter;
        iou[k] = inter * frcp(tarea + pw * ph - inter);
    }

    const bool b1 = (iou[1] > iou[0]);     // tie -> box 0 (first-max)
    const float bx = b1 ? pbx[1] : pbx[0];
    const float by = b1 ? pby[1] : pby[0];
    const float bw = b1 ? pbw[1] : pbw[0];
    const float bh = b1 ? pbh[1] : pbh[0];
    const float conf_b = b1 ? conf1 : conf0;
    const float iou_b  = b1 ? iou[1] : iou[0];

    const float dx = bx - tox;
    const float dy = by - toy;
    const float dw = sqrtf(bw) - sqrtf(tw);
    const float dh = sqrtf(bh) - sqrtf(th);
    const float coord = dx * dx + dy * dy + dw * dw + dh * dh;
    const float d1 = conf_b - iou_b;
    const float d2 = 1.0f - cls_t;
    const float obj   = kWC * coord + d1 * d1 + d2 * d2;
    const float noobj = kWN * (conf0 * conf0 + conf1 * conf1);

    float v = (g == 1) ? obj : noobj;

    // wave64 shuffle reduce, cross-wave via tiny LDS, one atomic per block
    #pragma unroll
    for (int off = 32; off > 0; off >>= 1) v += __shfl_down(v, off, 64);
    if (lane == 0) wsum[wave] = v;
    __syncthreads();
    if (tid == 0) {
        atomicAdd(out, (wsum[0] + wsum[1] + wsum[2] + wsum[3]) * (1.0f / kB));
    }
}

} // namespace

extern "C" void kernel_launch(void* const* d_in, const int* in_sizes, int n_in,
                              void* d_out, int out_size, void* d_ws, size_t ws_size,
                              hipStream_t stream) {
    const float* pred = (const float*)d_in[0];
    const int*   grid = (const int*)d_in[1];
    const float* tbox = (const float*)d_in[2];
    const int*   tcls = (const int*)d_in[3];
    float* out = (float*)d_out;

    zero_kernel<<<1, 64, 0, stream>>>(out);
    yolo_loss_kernel<<<NBLK, TPB, 0, stream>>>(pred, grid, tbox, tcls, out);
}

// Round 4
// 167.827 us; speedup vs baseline: 1.0152x; 1.0152x over previous
//
#include <hip/hip_runtime.h>
#include <math.h>

namespace {

constexpr int kB    = 16384;
constexpr int kS0   = 7;
constexpr int kS1   = 7;
constexpr int kD    = 30;
constexpr int kCells = kB * kS0 * kS1;   // 802816
constexpr int TPB   = 256;
constexpr int NBLK  = kCells / TPB;      // 3136 (exact)
constexpr float kInv7 = 1.0f / 7.0f;
constexpr float kWC = 5.0f;
constexpr float kWN = 0.5f;

__device__ __forceinline__ float frcp(float x) {
    return __builtin_amdgcn_rcpf(x);     // v_rcp_f32, ~1e-7 rel err (2% tol)
}

__device__ __forceinline__ float sigm(float x) {
    return frcp(1.0f + __expf(-x));
}

// r14 = r10's tuned zero-LDS yolo body, VERBATIM, + fused finish.
// History: r11 (coalesced reg->LDS staging) 163.6us, r13 (global_load_lds
// staging + barrier drain) 170.4us — both LOSE to this direct-load structure
// (160.5us). Crack-cost theory dead twice over; the barrier-free per-wave
// dataflow wins in this latency-bound regime.
// The only untested lever on top of r10: drop the dependent 1-block
// finish_kernel (full-grid-drain tail + dispatch, ~4-6us) in favor of one
// atomicAdd per block into out[0], zeroed by a 1-block kernel up front.
__global__ void zero_kernel(float* __restrict__ out) {
    if (threadIdx.x == 0) out[0] = 0.0f;
}

__global__ void __launch_bounds__(TPB, 4) yolo_loss_kernel(
    const float* __restrict__ pred,
    const int*   __restrict__ grid,
    const float* __restrict__ tbox,
    const int*   __restrict__ tcls,
    float* __restrict__ out)
{
    __shared__ float wsum[TPB / 64];      // reduction only (16 B)

    const int tid  = threadIdx.x;
    const int cell = blockIdx.x * TPB + tid;
    const int wave = tid >> 6;
    const int lane = tid & 63;

    // --- 15 independent float2 loads straight into f[] + the 3 small loads;
    // everything issued before any use.
    const float2* __restrict__ p2 =
        reinterpret_cast<const float2*>(pred + (size_t)cell * kD);

    float f[kD];
    #pragma unroll
    for (int q = 0; q < kD / 2; ++q) {
        const float2 t = p2[q];
        f[2 * q]     = t.x;
        f[2 * q + 1] = t.y;
    }

    const float4 tb4 = reinterpret_cast<const float4*>(tbox)[cell];
    const int g  = grid[cell];
    const int tc = tcls[cell];

    __builtin_amdgcn_sched_barrier(0);    // 18 loads in flight; none sunk

    const int cj = cell % kS1;            // column -> xg
    const int ci = (cell / kS1) % kS0;    // row    -> yg
    const float tox = tb4.x, toy = tb4.y, tw = tb4.z, th = tb4.w;

    const float conf0 = sigm(f[0]);
    const float conf1 = sigm(f[1]);
    float pbx[2], pby[2], pbw[2], pbh[2];
    #pragma unroll
    for (int k = 0; k < 2; ++k) {
        pbx[k] = sigm(f[2 + 4 * k + 0]);
        pby[k] = sigm(f[2 + 4 * k + 1]);
        pbw[k] = sigm(f[2 + 4 * k + 2]);
        pbh[k] = sigm(f[2 + 4 * k + 3]);
    }

    // --- softmax over 20 classes, no max-subtraction (inputs ~N(0,1):
    // exp <= ~e^6, 20-term fp32 sum nowhere near overflow) ---
    float csum = 0.0f, et = 0.0f;
    #pragma unroll
    for (int q = 0; q < 20; ++q) {
        const float e = __expf(f[10 + q]);
        csum += e;
        et = (q == tc) ? e : et;          // constant q -> cndmask
    }
    const float cls_t = et * frcp(csum);

    // --- IOU of both predicted boxes vs target box ---
    const float x = (float)cj, y = (float)ci;
    const float tcx = (x + tox) * kInv7;
    const float tcy = (y + toy) * kInv7;
    const float thw = tw * 0.5f, thh = th * 0.5f;
    const float tarea = tw * th;

    float iou[2];
    #pragma unroll
    for (int k = 0; k < 2; ++k) {
        const float pcx = (x + pbx[k]) * kInv7;
        const float pcy = (y + pby[k]) * kInv7;
        const float pw = pbw[k], ph = pbh[k];
        const float tb_ = fminf(tcx + thw, pcx + pw * 0.5f) - fmaxf(tcx - thw, pcx - pw * 0.5f);
        const float lr_ = fminf(tcy + thh, pcy + ph * 0.5f) - fmaxf(tcy - thh, pcy - ph * 0.5f);
        float inter = tb_ * lr_;
        inter = (tb_ < 0.0f || lr_ < 0.0f) ? 0.0f : inter;
        iou[k] = inter * frcp(tarea + pw * ph - inter);
    }

    const bool b1 = (iou[1] > iou[0]);     // tie -> box 0 (first-max)
    const float bx = b1 ? pbx[1] : pbx[0];
    const float by = b1 ? pby[1] : pby[0];
    const float bw = b1 ? pbw[1] : pbw[0];
    const float bh = b1 ? pbh[1] : pbh[0];
    const float conf_b = b1 ? conf1 : conf0;
    const float iou_b  = b1 ? iou[1] : iou[0];

    const float dx = bx - tox;
    const float dy = by - toy;
    const float dw = sqrtf(bw) - sqrtf(tw);
    const float dh = sqrtf(bh) - sqrtf(th);
    const float coord = dx * dx + dy * dy + dw * dw + dh * dh;
    const float d1 = conf_b - iou_b;
    const float d2 = 1.0f - cls_t;
    const float obj   = kWC * coord + d1 * d1 + d2 * d2;
    const float noobj = kWN * (conf0 * conf0 + conf1 * conf1);

    float v = (g == 1) ? obj : noobj;

    // --- wave64 shuffle reduce, cross-wave via tiny LDS, one atomic/block ---
    #pragma unroll
    for (int off = 32; off > 0; off >>= 1) v += __shfl_down(v, off, 64);
    if (lane == 0) wsum[wave] = v;
    __syncthreads();
    if (tid == 0) {
        atomicAdd(out, (wsum[0] + wsum[1] + wsum[2] + wsum[3]) * (1.0f / kB));
    }
}

} // namespace

extern "C" void kernel_launch(void* const* d_in, const int* in_sizes, int n_in,
                              void* d_out, int out_size, void* d_ws, size_t ws_size,
                              hipStream_t stream) {
    const float* pred = (const float*)d_in[0];
    const int*   grid = (const int*)d_in[1];
    const float* tbox = (const float*)d_in[2];
    const int*   tcls = (const int*)d_in[3];
    float* out = (float*)d_out;

    zero_kernel<<<1, 64, 0, stream>>>(out);
    yolo_loss_kernel<<<NBLK, TPB, 0, stream>>>(pred, grid, tbox, tcls, out);
}

// Round 5
// 161.881 us; speedup vs baseline: 1.0525x; 1.0367x over previous
//
#include <hip/hip_runtime.h>
#include <math.h>

namespace {

constexpr int kB    = 16384;
constexpr int kS0   = 7;
constexpr int kS1   = 7;
constexpr int kD    = 30;
constexpr int kCells = kB * kS0 * kS1;   // 802816
constexpr int TPB   = 256;
constexpr int CPT   = 2;                 // cells per thread (240 B = 15 float4)
constexpr int NBLK  = kCells / (TPB * CPT);   // 1568 (exact)
constexpr float kInv7 = 1.0f / 7.0f;
constexpr float kWC = 5.0f;
constexpr float kWN = 0.5f;

__device__ __forceinline__ float frcp(float x) {
    return __builtin_amdgcn_rcpf(x);     // v_rcp_f32, ~1e-7 rel err (2% tol)
}

__device__ __forceinline__ float sigm(float x) {
    return frcp(1.0f + __expf(-x));
}

// r15: r10's barrier-free direct-load structure, 2 cells/thread.
// History: r11 (coalesced LDS) 163.6, r13 (global_load_lds) 170.4,
// r14 (atomic finish) 167.8 vs r10 160.5 -> crack/staging/finish theories
// all dead; finish kernel reverted to r10's proven form.
// This round's axis: per-cell VMEM issue count + per-wave fixed overhead.
// Two adjacent cells = 240 B = 15 aligned dwordx4 -> half the VMEM issues
// per cell, half the waves, same in-flight bytes per CU (123 KB).
__global__ void __launch_bounds__(TPB, 4) yolo_loss_kernel(
    const float* __restrict__ pred,
    const int*   __restrict__ grid,
    const float* __restrict__ tbox,
    const int*   __restrict__ tcls,
    float* __restrict__ partials)   // NBLK f32 in d_ws (all overwritten)
{
    __shared__ float wsum[TPB / 64];      // reduction only (16 B)

    const int tid  = threadIdx.x;
    const int gt   = blockIdx.x * TPB + tid;   // thread id over kCells/2
    const int wave = tid >> 6;
    const int lane = tid & 63;

    // --- 15 float4 loads (2 cells, 240 B, 16B-aligned) + 4 small loads;
    // everything issued before any use.
    const float4* __restrict__ gp4 =
        reinterpret_cast<const float4*>(pred) + (size_t)gt * 15;

    float f[2 * kD];
    #pragma unroll
    for (int q = 0; q < 15; ++q) {
        const float4 t4 = gp4[q];
        f[4 * q + 0] = t4.x;
        f[4 * q + 1] = t4.y;
        f[4 * q + 2] = t4.z;
        f[4 * q + 3] = t4.w;
    }

    const float4* __restrict__ tbp =
        reinterpret_cast<const float4*>(tbox) + (size_t)gt * 2;
    const float4 tbA = tbp[0];
    const float4 tbB = tbp[1];
    const int2 g2  = reinterpret_cast<const int2*>(grid)[gt];
    const int2 tc2 = reinterpret_cast<const int2*>(tcls)[gt];

    __builtin_amdgcn_sched_barrier(0);    // 19 loads in flight; none sunk

    float v = 0.0f;

    #pragma unroll
    for (int h = 0; h < 2; ++h) {
        const float* fc = &f[kD * h];     // constant offsets after unroll
        const int   cellc = 2 * gt + h;
        const float4 tb4 = (h == 0) ? tbA : tbB;
        const int   g  = (h == 0) ? g2.x : g2.y;
        const int   tc = (h == 0) ? tc2.x : tc2.y;

        const int cj = cellc % kS1;       // column -> xg
        const int ci = (cellc / kS1) % kS0;  // row -> yg
        const float tox = tb4.x, toy = tb4.y, tw = tb4.z, th = tb4.w;

        const float conf0 = sigm(fc[0]);
        const float conf1 = sigm(fc[1]);
        float pbx[2], pby[2], pbw[2], pbh[2];
        #pragma unroll
        for (int k = 0; k < 2; ++k) {
            pbx[k] = sigm(fc[2 + 4 * k + 0]);
            pby[k] = sigm(fc[2 + 4 * k + 1]);
            pbw[k] = sigm(fc[2 + 4 * k + 2]);
            pbh[k] = sigm(fc[2 + 4 * k + 3]);
        }

        // softmax over 20 classes, no max-subtraction (inputs ~N(0,1):
        // exp <= ~e^6, 20-term fp32 sum nowhere near overflow)
        float csum = 0.0f, et = 0.0f;
        #pragma unroll
        for (int q = 0; q < 20; ++q) {
            const float e = __expf(fc[10 + q]);
            csum += e;
            et = (q == tc) ? e : et;      // constant q -> cndmask
        }
        const float cls_t = et * frcp(csum);

        // IOU of both predicted boxes vs target box
        const float x = (float)cj, y = (float)ci;
        const float tcx = (x + tox) * kInv7;
        const float tcy = (y + toy) * kInv7;
        const float thw = tw * 0.5f, thh = th * 0.5f;
        const float tarea = tw * th;

        float iou[2];
        #pragma unroll
        for (int k = 0; k < 2; ++k) {
            const float pcx = (x + pbx[k]) * kInv7;
            const float pcy = (y + pby[k]) * kInv7;
            const float pw = pbw[k], ph = pbh[k];
            const float tb_ = fminf(tcx + thw, pcx + pw * 0.5f) - fmaxf(tcx - thw, pcx - pw * 0.5f);
            const float lr_ = fminf(tcy + thh, pcy + ph * 0.5f) - fmaxf(tcy - thh, pcy - ph * 0.5f);
            float inter = tb_ * lr_;
            inter = (tb_ < 0.0f || lr_ < 0.0f) ? 0.0f : inter;
            iou[k] = inter * frcp(tarea + pw * ph - inter);
        }

        const bool b1 = (iou[1] > iou[0]);   // tie -> box 0 (first-max)
        const float bx = b1 ? pbx[1] : pbx[0];
        const float by = b1 ? pby[1] : pby[0];
        const float bw = b1 ? pbw[1] : pbw[0];
        const float bh = b1 ? pbh[1] : pbh[0];
        const float conf_b = b1 ? conf1 : conf0;
        const float iou_b  = b1 ? iou[1] : iou[0];

        const float dx = bx - tox;
        const float dy = by - toy;
        const float dw = sqrtf(bw) - sqrtf(tw);
        const float dh = sqrtf(bh) - sqrtf(th);
        const float coord = dx * dx + dy * dy + dw * dw + dh * dh;
        const float d1 = conf_b - iou_b;
        const float d2 = 1.0f - cls_t;
        const float obj   = kWC * coord + d1 * d1 + d2 * d2;
        const float noobj = kWN * (conf0 * conf0 + conf1 * conf1);

        v += (g == 1) ? obj : noobj;
    }

    // --- wave64 shuffle reduce, cross-wave via tiny LDS, plain store ---
    #pragma unroll
    for (int off = 32; off > 0; off >>= 1) v += __shfl_down(v, off, 64);
    if (lane == 0) wsum[wave] = v;
    __syncthreads();
    if (tid == 0) {
        partials[blockIdx.x] = wsum[0] + wsum[1] + wsum[2] + wsum[3];
    }
}

__global__ void __launch_bounds__(256) finish_kernel(
    const float* __restrict__ partials, float* __restrict__ out)
{
    __shared__ float wsum[4];
    const int tid = threadIdx.x;
    float v = 0.0f;
    for (int i = tid; i < NBLK; i += 256) v += partials[i];  // <=7 iters
    #pragma unroll
    for (int off = 32; off > 0; off >>= 1) v += __shfl_down(v, off, 64);
    if ((tid & 63) == 0) wsum[tid >> 6] = v;
    __syncthreads();
    if (tid == 0) out[0] = (wsum[0] + wsum[1] + wsum[2] + wsum[3]) * (1.0f / kB);
}

} // namespace

extern "C" void kernel_launch(void* const* d_in, const int* in_sizes, int n_in,
                              void* d_out, int out_size, void* d_ws, size_t ws_size,
                              hipStream_t stream) {
    const float* pred = (const float*)d_in[0];
    const int*   grid = (const int*)d_in[1];
    const float* tbox = (const float*)d_in[2];
    const int*   tcls = (const int*)d_in[3];
    float* out      = (float*)d_out;
    float* partials = (float*)d_ws;       // NBLK f32; fully overwritten

    yolo_loss_kernel<<<NBLK, TPB, 0, stream>>>(pred, grid, tbox, tcls, partials);
    finish_kernel<<<1, 256, 0, stream>>>(partials, out);
}